// Round 5
// baseline (8075.429 us; speedup 1.0000x reference)
//
#include <hip/hip_runtime.h>
#include <stdint.h>

#define SLEN 4096
#define CLEN 16
#define EDIM 256
#define HDIM 512
#define CHD  4
#define NLBL 64
#define KIN  260   /* EDIM + CHD */
#define G4H  2048  /* 4*HDIM */

typedef unsigned long long u64;

__device__ __forceinline__ float sigf(float x){ return 1.0f/(1.0f+__expf(-x)); }
/* fast tanh: 1 - 2/(e^(2x)+1); saturates correctly for |x| large */
__device__ __forceinline__ float ftanh(float x){
  float e = __expf(2.0f*x);
  return 1.0f - 2.0f/(e+1.0f);
}

/* ---------------- char-level LSTM: one thread per word ---------------- */
__global__ void k_char_lstm(const float* __restrict__ chars, const int* __restrict__ lens,
                            const float* __restrict__ Wih, const float* __restrict__ Whh,
                            const float* __restrict__ bih, const float* __restrict__ bhh,
                            float* __restrict__ h_char){
  int s = blockIdx.x*blockDim.x + threadIdx.x;
  if (s >= SLEN) return;
  float wih[16], bb[16], whh[16][4];
  #pragma unroll
  for(int r=0;r<16;r++){
    wih[r]=Wih[r]; bb[r]=bih[r]+bhh[r];
    #pragma unroll
    for(int k=0;k<4;k++) whh[r][k]=Whh[r*4+k];
  }
  float x[16];
  #pragma unroll
  for(int i=0;i<4;i++){
    float4 v = *(const float4*)&chars[s*CLEN + 4*i];
    x[4*i+0]=v.x; x[4*i+1]=v.y; x[4*i+2]=v.z; x[4*i+3]=v.w;
  }
  float h[4]={0,0,0,0}, c[4]={0,0,0,0};
  int len = lens[s];
  #pragma unroll 1
  for(int t=0;t<CLEN;t++){
    float g[16];
    #pragma unroll
    for(int r=0;r<16;r++){
      float a = fmaf(x[t], wih[r], bb[r]);
      #pragma unroll
      for(int k=0;k<4;k++) a = fmaf(h[k], whh[r][k], a);
      g[r]=a;
    }
    bool m = t < len;
    #pragma unroll
    for(int j=0;j<4;j++){
      float ig=sigf(g[j]), fg=sigf(g[4+j]), gg=ftanh(g[8+j]), og=sigf(g[12+j]);
      float cn = fg*c[j] + ig*gg;
      float hn = og*ftanh(cn);
      if(m){ c[j]=cn; h[j]=hn; }
    }
  }
  #pragma unroll
  for(int j=0;j<4;j++) h_char[s*CHD+j]=h[j];
}

/* ------------- gather emb rows + h_char into word_in[4096][260] ------------- */
__global__ void k_gather(const int* __restrict__ sent, const float* __restrict__ emb,
                         const float* __restrict__ h_char, float* __restrict__ win){
  int s = blockIdx.x; int l = threadIdx.x; /* 64 threads */
  int row = sent[s];
  float4 v = *(const float4*)&emb[(size_t)row*EDIM + 4*l];
  *(float4*)&win[(size_t)s*KIN + 4*l] = v;
  if (l < CHD) win[(size_t)s*KIN + EDIM + l] = h_char[s*CHD + l];
}

/* ------------- gx = word_in @ W_ih_w.T  (M=4096,N=2048,K=260) ------------- */
#define BK 20
__global__ __launch_bounds__(256) void k_gemm_gx(const float* __restrict__ win,
                          const float* __restrict__ Wihw, float* __restrict__ gx){
  __shared__ float As[BK][68];
  __shared__ float Bs[BK][68];
  int s0 = blockIdx.x*64, n0 = blockIdx.y*64;
  int tid = threadIdx.x;
  int tm = tid>>4, tn = tid&15;
  float acc[4][4] = {};
  for(int k0=0;k0<KIN;k0+=BK){
    __syncthreads();
    #pragma unroll
    for(int i=0;i<5;i++){
      int e = tid + i*256;
      int m = e/BK, kk = e - m*BK;
      As[kk][m] = win[(size_t)(s0+m)*KIN + k0+kk];
      Bs[kk][m] = Wihw[(size_t)(n0+m)*KIN + k0+kk];
    }
    __syncthreads();
    #pragma unroll
    for(int kk=0;kk<BK;kk++){
      float4 a4 = *(const float4*)&As[kk][tm*4];
      float4 b4 = *(const float4*)&Bs[kk][tn*4];
      float av[4]={a4.x,a4.y,a4.z,a4.w};
      float bv[4]={b4.x,b4.y,b4.z,b4.w};
      #pragma unroll
      for(int i=0;i<4;i++)
        #pragma unroll
        for(int j=0;j<4;j++)
          acc[i][j] = fmaf(av[i], bv[j], acc[i][j]);
    }
  }
  #pragma unroll
  for(int i=0;i<4;i++){
    float4 o; o.x=acc[i][0]; o.y=acc[i][1]; o.z=acc[i][2]; o.w=acc[i][3];
    *(float4*)&gx[(size_t)(s0+tm*4+i)*G4H + n0 + tn*4] = o;
  }
}

/* ------------- word-level LSTM: 32 persistent WGs (R1 skeleton) -------------
   r = tid>>3 (gate row 0..63, r = gate*16+jl), cch = tid&7 (64-wide k chunk).
   Writers: wave-0 lanes tid<16 -> ONE coalesced 128B comm store (R1-proven).
   Both syncs are raw s_barrier + lgkmcnt(0) (no vmcnt drain), enabling a
   3-deep rotating poll whose dangling loads are sunk at the end of the body. */
__global__ __launch_bounds__(512) void k_word_lstm(const float* __restrict__ gx,
    const float* __restrict__ Whh, const float* __restrict__ bih, const float* __restrict__ bhh,
    u64* __restrict__ comm){
  __shared__ float h_lds[2][8*68];
  __shared__ float gatebuf[64];
  const int tid  = threadIdx.x;
  const int g    = blockIdx.x;
  const int r    = tid>>3;
  const int cch  = tid&7;
  const int gate = r>>4, jl = r&15;
  const int R    = gate*HDIM + g*16 + jl;
  const int gi   = g*16 + tid;          /* valid for tid<16 (writers) */
  /* resident weight slice: W_hh_w[R][cch*64 .. +64) in 64 VGPRs */
  float4 w4[16];
  #pragma unroll
  for(int i=0;i<16;i++) w4[i] = *(const float4*)&Whh[(size_t)R*HDIM + cch*64 + 4*i];
  float cst = 0.f;
  float bsum[4], gxv[4];
  if (tid<16){
    #pragma unroll
    for(int q=0;q<4;q++){
      bsum[q] = bih[q*HDIM + gi] + bhh[q*HDIM + gi];
      gxv[q]  = gx[(size_t)0*G4H + q*HDIM + gi];   /* t=0 prefetch */
    }
  }
  u64 dang1 = 0, dang2 = 0;   /* dangling poll loads, kept live to end of body */

  #pragma unroll 1
  for(int t=0;t<SLEN;t++){
    /* --- poll h_t[tid]: 3-deep rotating tag-match on packed {tag,value} --- */
    float hv = 0.f;
    if (t>0){
      const u64* slot = &comm[(size_t)t*HDIM + tid];
      u64 v0 = __hip_atomic_load(slot, __ATOMIC_RELAXED, __HIP_MEMORY_SCOPE_AGENT);
      u64 v1 = __hip_atomic_load(slot, __ATOMIC_RELAXED, __HIP_MEMORY_SCOPE_AGENT);
      u64 v2 = __hip_atomic_load(slot, __ATOMIC_RELAXED, __HIP_MEMORY_SCOPE_AGENT);
      while ((unsigned)(v0>>32) != (unsigned)t){
        v0 = v1; v1 = v2;
        v2 = __hip_atomic_load(slot, __ATOMIC_RELAXED, __HIP_MEMORY_SCOPE_AGENT);
      }
      union{unsigned u; float f;} cv; cv.u = (unsigned)v0; hv = cv.f;
      dang1 = v1; dang2 = v2;
    }
    const int par = t&1;
    h_lds[par][(tid>>6)*68 + (tid&63)] = hv;
    asm volatile("s_waitcnt lgkmcnt(0)" ::: "memory");
    __builtin_amdgcn_s_barrier();              /* sync #1: no vmcnt drain */
    /* --- 64-MAC partial dot from resident weights --- */
    float acc = 0.f;
    #pragma unroll
    for(int i=0;i<16;i++){
      float4 hh = *(const float4*)&h_lds[par][cch*68 + 4*i];
      acc = fmaf(w4[i].x, hh.x, acc);
      acc = fmaf(w4[i].y, hh.y, acc);
      acc = fmaf(w4[i].z, hh.z, acc);
      acc = fmaf(w4[i].w, hh.w, acc);
    }
    acc += __shfl_xor(acc,1);
    acc += __shfl_xor(acc,2);
    acc += __shfl_xor(acc,4);
    if (cch==0) gatebuf[r] = acc;
    asm volatile("s_waitcnt lgkmcnt(0)" ::: "memory");
    __builtin_amdgcn_s_barrier();              /* sync #2: no vmcnt drain */
    /* --- wave 0: gather gates, pointwise, single coalesced 128B store --- */
    if (tid < 64){
      float gv  = gatebuf[tid];
      float a16 = __shfl_down(gv,16);
      float a32 = __shfl_down(gv,32);
      float a48 = __shfl_down(gv,48);
      if (tid<16){
        float gi_ = gv  + gxv[0] + bsum[0];
        float gf_ = a16 + gxv[1] + bsum[1];
        float gg_ = a32 + gxv[2] + bsum[2];
        float go_ = a48 + gxv[3] + bsum[3];
        float cn = sigf(gf_)*cst + sigf(gi_)*ftanh(gg_);
        float hn = sigf(go_)*ftanh(cn);
        cst = cn;
        union{float f; unsigned u;} hb; hb.f = hn;
        u64 pk = ((u64)(unsigned)(t+1)<<32) | (u64)hb.u;
        __hip_atomic_store(&comm[(size_t)(t+1)*HDIM + gi], pk,
                           __ATOMIC_RELAXED, __HIP_MEMORY_SCOPE_AGENT);
        /* prefetch gx for t+1 AFTER the store (in flight across next poll) */
        if (t+1 < SLEN){
          #pragma unroll
          for(int q=0;q<4;q++) gxv[q] = gx[(size_t)(t+1)*G4H + q*HDIM + gi];
        }
      }
    }
    /* sink: keeps dangling poll-load regs live; their vmcnt wait lands here,
       ~1000+ cy after issue, where it is free */
    asm volatile("" :: "v"(dang1), "v"(dang2));
  }
}

/* ------------- logits + log_softmax (h read from comm low words) ------------- */
__global__ __launch_bounds__(256) void k_out(const u64* __restrict__ comm,
        const float* __restrict__ Wout, const float* __restrict__ bout,
        float* __restrict__ out){
  __shared__ float hsub[HDIM];
  __shared__ float lg[NLBL];
  int s = blockIdx.x, tid = threadIdx.x;
  {
    union{unsigned u; float f;} a, b;
    a.u = (unsigned)comm[(size_t)(s+1)*HDIM + tid];
    b.u = (unsigned)comm[(size_t)(s+1)*HDIM + tid + 256];
    hsub[tid] = a.f; hsub[tid+256] = b.f;
  }
  __syncthreads();
  int l = tid>>2, q = tid&3;
  float a = 0.f;
  const float* wrp = &Wout[(size_t)l*HDIM + q*128];
  const float* hr = &hsub[q*128];
  #pragma unroll 8
  for(int i=0;i<128;i++) a = fmaf(hr[i], wrp[i], a);
  a += __shfl_xor(a,1);
  a += __shfl_xor(a,2);
  if (q==0) lg[l] = a + bout[l];
  __syncthreads();
  if (tid < NLBL){
    float x = lg[tid];
    float mx = x;
    #pragma unroll
    for(int m=32;m>=1;m>>=1) mx = fmaxf(mx, __shfl_xor(mx,m));
    float ex = __expf(x-mx);
    float sm = ex;
    #pragma unroll
    for(int m=32;m>=1;m>>=1) sm += __shfl_xor(sm,m);
    out[(size_t)s*NLBL + tid] = x - mx - __logf(sm);
  }
}

extern "C" void kernel_launch(void* const* d_in, const int* in_sizes, int n_in,
                              void* d_out, int out_size, void* d_ws, size_t ws_size,
                              hipStream_t stream){
  const int*   sent  = (const int*)d_in[0];
  const float* chars = (const float*)d_in[1];
  const int*   lens  = (const int*)d_in[2];
  const float* emb   = (const float*)d_in[3];
  const float* Wihc  = (const float*)d_in[4];
  const float* Whhc  = (const float*)d_in[5];
  const float* bihc  = (const float*)d_in[6];
  const float* bhhc  = (const float*)d_in[7];
  const float* Wihw  = (const float*)d_in[8];
  const float* Whhw  = (const float*)d_in[9];
  const float* bihw  = (const float*)d_in[10];
  const float* bhhw  = (const float*)d_in[11];
  const float* Wout  = (const float*)d_in[12];
  const float* bout  = (const float*)d_in[13];
  float* out = (float*)d_out;

  /* workspace (floats): h_char 16384 | word_in 4096*260 | gx 4096*2048 | comm 4097*512 u64
     comm tags are 1..4096; the 0xAA poison can never match -> no memset needed */
  float* h_char = (float*)d_ws;
  float* win    = h_char + 16384;
  float* gx     = win + (size_t)SLEN*KIN;
  u64*   comm   = (u64*)(gx + (size_t)SLEN*G4H);

  k_char_lstm<<<SLEN/256, 256, 0, stream>>>(chars,lens,Wihc,Whhc,bihc,bhhc,h_char);
  k_gather<<<SLEN, 64, 0, stream>>>(sent,emb,h_char,win);
  k_gemm_gx<<<dim3(SLEN/64, G4H/64), 256, 0, stream>>>(win,Wihw,gx);
  k_word_lstm<<<HDIM/16, 512, 0, stream>>>(gx,Whhw,bihw,bhhw,comm);
  k_out<<<SLEN, 256, 0, stream>>>(comm,Wout,bout,out);
}

// Round 6
// 7959.309 us; speedup vs baseline: 1.0146x; 1.0146x over previous
//
#include <hip/hip_runtime.h>
#include <stdint.h>

#define SLEN 4096
#define CLEN 16
#define EDIM 256
#define HDIM 512
#define CHD  4
#define NLBL 64
#define KIN  260   /* EDIM + CHD */
#define G4H  2048  /* 4*HDIM */

typedef unsigned long long u64;

__device__ __forceinline__ float sigf(float x){ return 1.0f/(1.0f+__expf(-x)); }
/* fast tanh: 1 - 2/(e^(2x)+1); saturates correctly for |x| large */
__device__ __forceinline__ float ftanh(float x){
  float e = __expf(2.0f*x);
  return 1.0f - 2.0f/(e+1.0f);
}

/* ---------------- char-level LSTM: one thread per word ---------------- */
__global__ void k_char_lstm(const float* __restrict__ chars, const int* __restrict__ lens,
                            const float* __restrict__ Wih, const float* __restrict__ Whh,
                            const float* __restrict__ bih, const float* __restrict__ bhh,
                            float* __restrict__ h_char){
  int s = blockIdx.x*blockDim.x + threadIdx.x;
  if (s >= SLEN) return;
  float wih[16], bb[16], whh[16][4];
  #pragma unroll
  for(int r=0;r<16;r++){
    wih[r]=Wih[r]; bb[r]=bih[r]+bhh[r];
    #pragma unroll
    for(int k=0;k<4;k++) whh[r][k]=Whh[r*4+k];
  }
  float x[16];
  #pragma unroll
  for(int i=0;i<4;i++){
    float4 v = *(const float4*)&chars[s*CLEN + 4*i];
    x[4*i+0]=v.x; x[4*i+1]=v.y; x[4*i+2]=v.z; x[4*i+3]=v.w;
  }
  float h[4]={0,0,0,0}, c[4]={0,0,0,0};
  int len = lens[s];
  #pragma unroll 1
  for(int t=0;t<CLEN;t++){
    float g[16];
    #pragma unroll
    for(int r=0;r<16;r++){
      float a = fmaf(x[t], wih[r], bb[r]);
      #pragma unroll
      for(int k=0;k<4;k++) a = fmaf(h[k], whh[r][k], a);
      g[r]=a;
    }
    bool m = t < len;
    #pragma unroll
    for(int j=0;j<4;j++){
      float ig=sigf(g[j]), fg=sigf(g[4+j]), gg=ftanh(g[8+j]), og=sigf(g[12+j]);
      float cn = fg*c[j] + ig*gg;
      float hn = og*ftanh(cn);
      if(m){ c[j]=cn; h[j]=hn; }
    }
  }
  #pragma unroll
  for(int j=0;j<4;j++) h_char[s*CHD+j]=h[j];
}

/* ------------- gather emb rows + h_char into word_in[4096][260] ------------- */
__global__ void k_gather(const int* __restrict__ sent, const float* __restrict__ emb,
                         const float* __restrict__ h_char, float* __restrict__ win){
  int s = blockIdx.x; int l = threadIdx.x; /* 64 threads */
  int row = sent[s];
  float4 v = *(const float4*)&emb[(size_t)row*EDIM + 4*l];
  *(float4*)&win[(size_t)s*KIN + 4*l] = v;
  if (l < CHD) win[(size_t)s*KIN + EDIM + l] = h_char[s*CHD + l];
}

/* ------------- gx = word_in @ W_ih_w.T  (M=4096,N=2048,K=260) ------------- */
#define BK 20
__global__ __launch_bounds__(256) void k_gemm_gx(const float* __restrict__ win,
                          const float* __restrict__ Wihw, float* __restrict__ gx){
  __shared__ float As[BK][68];
  __shared__ float Bs[BK][68];
  int s0 = blockIdx.x*64, n0 = blockIdx.y*64;
  int tid = threadIdx.x;
  int tm = tid>>4, tn = tid&15;
  float acc[4][4] = {};
  for(int k0=0;k0<KIN;k0+=BK){
    __syncthreads();
    #pragma unroll
    for(int i=0;i<5;i++){
      int e = tid + i*256;
      int m = e/BK, kk = e - m*BK;
      As[kk][m] = win[(size_t)(s0+m)*KIN + k0+kk];
      Bs[kk][m] = Wihw[(size_t)(n0+m)*KIN + k0+kk];
    }
    __syncthreads();
    #pragma unroll
    for(int kk=0;kk<BK;kk++){
      float4 a4 = *(const float4*)&As[kk][tm*4];
      float4 b4 = *(const float4*)&Bs[kk][tn*4];
      float av[4]={a4.x,a4.y,a4.z,a4.w};
      float bv[4]={b4.x,b4.y,b4.z,b4.w};
      #pragma unroll
      for(int i=0;i<4;i++)
        #pragma unroll
        for(int j=0;j<4;j++)
          acc[i][j] = fmaf(av[i], bv[j], acc[i][j]);
    }
  }
  #pragma unroll
  for(int i=0;i<4;i++){
    float4 o; o.x=acc[i][0]; o.y=acc[i][1]; o.z=acc[i][2]; o.w=acc[i][3];
    *(float4*)&gx[(size_t)(s0+tm*4+i)*G4H + n0 + tn*4] = o;
  }
}

/* ------------- word-level LSTM: 16 persistent WGs (R1 sync skeleton) -------------
   WG g owns h indices [32g, 32g+32): 128 gate rows.
   Thread map: r = tid>>2 (row 0..127, r = gate*32+jl), kc = tid&3 (128-wide chunk).
   Per-thread: 128 resident weight VGPRs, 128 MACs. Reduction: 2x shfl_xor.
   Writers: wave-0 lanes tid<32 -> ONE coalesced 256B comm store.
   Sync: two __syncthreads (R1-proven). Poll: 1-deep (R1-proven; deeper polls
   measured WORSE: congestion delays producer-store visibility). */
__global__ __launch_bounds__(512) void k_word_lstm(const float* __restrict__ gx,
    const float* __restrict__ Whh, const float* __restrict__ bih, const float* __restrict__ bhh,
    u64* __restrict__ comm){
  __shared__ float h_lds[2][4*132];   /* 4 chunks of 128, +4 pad -> conflict-free b128 reads */
  __shared__ float gatebuf[128];
  const int tid  = threadIdx.x;
  const int g    = blockIdx.x;        /* 0..15 */
  const int r    = tid>>2;            /* gate row 0..127 */
  const int kc   = tid&3;             /* 128-wide k chunk */
  const int gate = r>>5, jl = r&31;
  const int R    = gate*HDIM + g*32 + jl;
  const int gi   = g*32 + tid;        /* valid for tid<32 (writers) */
  /* resident weight slice: W_hh_w[R][kc*128 .. +128) in 128 VGPRs */
  float4 w4[32];
  #pragma unroll
  for(int i=0;i<32;i++) w4[i] = *(const float4*)&Whh[(size_t)R*HDIM + kc*128 + 4*i];
  float cst = 0.f;
  float bsum[4], gxv[4];
  if (tid<32){
    #pragma unroll
    for(int q=0;q<4;q++) bsum[q] = bih[q*HDIM + gi] + bhh[q*HDIM + gi];
  }

  #pragma unroll 1
  for(int t=0;t<SLEN;t++){
    /* gx prefetch for this step, in flight during the poll */
    if (tid<32){
      #pragma unroll
      for(int q=0;q<4;q++) gxv[q] = gx[(size_t)t*G4H + q*HDIM + gi];
    }
    /* poll h_t[tid]: 1-deep tag-match on packed {tag,value} (R1-proven) */
    float hv = 0.f;
    if (t>0){
      const u64* slot = &comm[(size_t)t*HDIM + tid];
      u64 v;
      do { v = __hip_atomic_load(slot, __ATOMIC_RELAXED, __HIP_MEMORY_SCOPE_AGENT); }
      while ((unsigned)(v>>32) != (unsigned)t);
      union{unsigned u; float f;} cv; cv.u = (unsigned)v; hv = cv.f;
    }
    const int par = t&1;
    h_lds[par][(tid>>7)*132 + (tid&127)] = hv;
    __syncthreads();
    /* 128-MAC partial dot from resident weights */
    float acc = 0.f;
    #pragma unroll
    for(int i=0;i<32;i++){
      float4 hh = *(const float4*)&h_lds[par][kc*132 + 4*i];
      acc = fmaf(w4[i].x, hh.x, acc);
      acc = fmaf(w4[i].y, hh.y, acc);
      acc = fmaf(w4[i].z, hh.z, acc);
      acc = fmaf(w4[i].w, hh.w, acc);
    }
    acc += __shfl_xor(acc,1);
    acc += __shfl_xor(acc,2);
    if (kc==0) gatebuf[r] = acc;
    __syncthreads();
    /* wave-0 writers: gather 4 gates from LDS, pointwise, coalesced 256B store */
    if (tid<32){
      float g0 = gatebuf[tid];
      float g1 = gatebuf[tid+32];
      float g2 = gatebuf[tid+64];
      float g3 = gatebuf[tid+96];
      float gi_ = g0 + gxv[0] + bsum[0];
      float gf_ = g1 + gxv[1] + bsum[1];
      float gg_ = g2 + gxv[2] + bsum[2];
      float go_ = g3 + gxv[3] + bsum[3];
      float cn = sigf(gf_)*cst + sigf(gi_)*ftanh(gg_);
      float hn = sigf(go_)*ftanh(cn);
      cst = cn;
      union{float f; unsigned u;} hb; hb.f = hn;
      u64 pk = ((u64)(unsigned)(t+1)<<32) | (u64)hb.u;
      __hip_atomic_store(&comm[(size_t)(t+1)*HDIM + gi], pk,
                         __ATOMIC_RELAXED, __HIP_MEMORY_SCOPE_AGENT);
    }
  }
}

/* ------------- logits + log_softmax (h read from comm low words) ------------- */
__global__ __launch_bounds__(256) void k_out(const u64* __restrict__ comm,
        const float* __restrict__ Wout, const float* __restrict__ bout,
        float* __restrict__ out){
  __shared__ float hsub[HDIM];
  __shared__ float lg[NLBL];
  int s = blockIdx.x, tid = threadIdx.x;
  {
    union{unsigned u; float f;} a, b;
    a.u = (unsigned)comm[(size_t)(s+1)*HDIM + tid];
    b.u = (unsigned)comm[(size_t)(s+1)*HDIM + tid + 256];
    hsub[tid] = a.f; hsub[tid+256] = b.f;
  }
  __syncthreads();
  int l = tid>>2, q = tid&3;
  float a = 0.f;
  const float* wrp = &Wout[(size_t)l*HDIM + q*128];
  const float* hr = &hsub[q*128];
  #pragma unroll 8
  for(int i=0;i<128;i++) a = fmaf(hr[i], wrp[i], a);
  a += __shfl_xor(a,1);
  a += __shfl_xor(a,2);
  if (q==0) lg[l] = a + bout[l];
  __syncthreads();
  if (tid < NLBL){
    float x = lg[tid];
    float mx = x;
    #pragma unroll
    for(int m=32;m>=1;m>>=1) mx = fmaxf(mx, __shfl_xor(mx,m));
    float ex = __expf(x-mx);
    float sm = ex;
    #pragma unroll
    for(int m=32;m>=1;m>>=1) sm += __shfl_xor(sm,m);
    out[(size_t)s*NLBL + tid] = x - mx - __logf(sm);
  }
}

extern "C" void kernel_launch(void* const* d_in, const int* in_sizes, int n_in,
                              void* d_out, int out_size, void* d_ws, size_t ws_size,
                              hipStream_t stream){
  const int*   sent  = (const int*)d_in[0];
  const float* chars = (const float*)d_in[1];
  const int*   lens  = (const int*)d_in[2];
  const float* emb   = (const float*)d_in[3];
  const float* Wihc  = (const float*)d_in[4];
  const float* Whhc  = (const float*)d_in[5];
  const float* bihc  = (const float*)d_in[6];
  const float* bhhc  = (const float*)d_in[7];
  const float* Wihw  = (const float*)d_in[8];
  const float* Whhw  = (const float*)d_in[9];
  const float* bihw  = (const float*)d_in[10];
  const float* bhhw  = (const float*)d_in[11];
  const float* Wout  = (const float*)d_in[12];
  const float* bout  = (const float*)d_in[13];
  float* out = (float*)d_out;

  /* workspace (floats): h_char 16384 | word_in 4096*260 | gx 4096*2048 | comm 4097*512 u64
     comm tags are 1..4096; the 0xAA poison can never match -> no memset needed */
  float* h_char = (float*)d_ws;
  float* win    = h_char + 16384;
  float* gx     = win + (size_t)SLEN*KIN;
  u64*   comm   = (u64*)(gx + (size_t)SLEN*G4H);

  k_char_lstm<<<SLEN/256, 256, 0, stream>>>(chars,lens,Wihc,Whhc,bihc,bhhc,h_char);
  k_gather<<<SLEN, 64, 0, stream>>>(sent,emb,h_char,win);
  k_gemm_gx<<<dim3(SLEN/64, G4H/64), 256, 0, stream>>>(win,Wihw,gx);
  k_word_lstm<<<HDIM/32, 512, 0, stream>>>(gx,Whhw,bihw,bhhw,comm);
  k_out<<<SLEN, 256, 0, stream>>>(comm,Wout,bout,out);
}

// Round 7
// 6489.725 us; speedup vs baseline: 1.2443x; 1.2264x over previous
//
#include <hip/hip_runtime.h>
#include <stdint.h>

#define SLEN 4096
#define CLEN 16
#define EDIM 256
#define HDIM 512
#define CHD  4
#define NLBL 64
#define KIN  260   /* EDIM + CHD */
#define G4H  2048  /* 4*HDIM */

typedef unsigned long long u64;

__device__ __forceinline__ float sigf(float x){ return 1.0f/(1.0f+__expf(-x)); }
/* fast tanh: 1 - 2/(e^(2x)+1); saturates correctly for |x| large */
__device__ __forceinline__ float ftanh(float x){
  float e = __expf(2.0f*x);
  return 1.0f - 2.0f/(e+1.0f);
}

/* ---------------- char-level LSTM: one thread per word ---------------- */
__global__ void k_char_lstm(const float* __restrict__ chars, const int* __restrict__ lens,
                            const float* __restrict__ Wih, const float* __restrict__ Whh,
                            const float* __restrict__ bih, const float* __restrict__ bhh,
                            float* __restrict__ h_char){
  int s = blockIdx.x*blockDim.x + threadIdx.x;
  if (s >= SLEN) return;
  float wih[16], bb[16], whh[16][4];
  #pragma unroll
  for(int r=0;r<16;r++){
    wih[r]=Wih[r]; bb[r]=bih[r]+bhh[r];
    #pragma unroll
    for(int k=0;k<4;k++) whh[r][k]=Whh[r*4+k];
  }
  float x[16];
  #pragma unroll
  for(int i=0;i<4;i++){
    float4 v = *(const float4*)&chars[s*CLEN + 4*i];
    x[4*i+0]=v.x; x[4*i+1]=v.y; x[4*i+2]=v.z; x[4*i+3]=v.w;
  }
  float h[4]={0,0,0,0}, c[4]={0,0,0,0};
  int len = lens[s];
  #pragma unroll 1
  for(int t=0;t<CLEN;t++){
    float g[16];
    #pragma unroll
    for(int r=0;r<16;r++){
      float a = fmaf(x[t], wih[r], bb[r]);
      #pragma unroll
      for(int k=0;k<4;k++) a = fmaf(h[k], whh[r][k], a);
      g[r]=a;
    }
    bool m = t < len;
    #pragma unroll
    for(int j=0;j<4;j++){
      float ig=sigf(g[j]), fg=sigf(g[4+j]), gg=ftanh(g[8+j]), og=sigf(g[12+j]);
      float cn = fg*c[j] + ig*gg;
      float hn = og*ftanh(cn);
      if(m){ c[j]=cn; h[j]=hn; }
    }
  }
  #pragma unroll
  for(int j=0;j<4;j++) h_char[s*CHD+j]=h[j];
}

/* ------------- gather emb rows + h_char into word_in[4096][260] ------------- */
__global__ void k_gather(const int* __restrict__ sent, const float* __restrict__ emb,
                         const float* __restrict__ h_char, float* __restrict__ win){
  int s = blockIdx.x; int l = threadIdx.x; /* 64 threads */
  int row = sent[s];
  float4 v = *(const float4*)&emb[(size_t)row*EDIM + 4*l];
  *(float4*)&win[(size_t)s*KIN + 4*l] = v;
  if (l < CHD) win[(size_t)s*KIN + EDIM + l] = h_char[s*CHD + l];
}

/* ------------- gx = word_in @ W_ih_w.T  (M=4096,N=2048,K=260) ------------- */
#define BK 20
__global__ __launch_bounds__(256) void k_gemm_gx(const float* __restrict__ win,
                          const float* __restrict__ Wihw, float* __restrict__ gx){
  __shared__ float As[BK][68];
  __shared__ float Bs[BK][68];
  int s0 = blockIdx.x*64, n0 = blockIdx.y*64;
  int tid = threadIdx.x;
  int tm = tid>>4, tn = tid&15;
  float acc[4][4] = {};
  for(int k0=0;k0<KIN;k0+=BK){
    __syncthreads();
    #pragma unroll
    for(int i=0;i<5;i++){
      int e = tid + i*256;
      int m = e/BK, kk = e - m*BK;
      As[kk][m] = win[(size_t)(s0+m)*KIN + k0+kk];
      Bs[kk][m] = Wihw[(size_t)(n0+m)*KIN + k0+kk];
    }
    __syncthreads();
    #pragma unroll
    for(int kk=0;kk<BK;kk++){
      float4 a4 = *(const float4*)&As[kk][tm*4];
      float4 b4 = *(const float4*)&Bs[kk][tn*4];
      float av[4]={a4.x,a4.y,a4.z,a4.w};
      float bv[4]={b4.x,b4.y,b4.z,b4.w};
      #pragma unroll
      for(int i=0;i<4;i++)
        #pragma unroll
        for(int j=0;j<4;j++)
          acc[i][j] = fmaf(av[i], bv[j], acc[i][j]);
    }
  }
  #pragma unroll
  for(int i=0;i<4;i++){
    float4 o; o.x=acc[i][0]; o.y=acc[i][1]; o.z=acc[i][2]; o.w=acc[i][3];
    *(float4*)&gx[(size_t)(s0+tm*4+i)*G4H + n0 + tn*4] = o;
  }
}

/* ------------- word-level LSTM: 32 persistent WGs (R1 skeleton, proven best)
   + 2-row PING-PONG comm: working set 16MB -> 8KB, permanently LLC-resident;
   kills the per-step compulsory-miss latency on the poll path.
   Safety: producer writes tag t+2 into row t&1 only after full h_{t+1} exists,
   which requires every WG past its step-t barrier = every reader already
   detected tag t. Exact tag match -> poison/stale never false-positive. */
__global__ __launch_bounds__(512) void k_word_lstm(const float* __restrict__ gx,
    const float* __restrict__ Whh, const float* __restrict__ bih, const float* __restrict__ bhh,
    u64* __restrict__ comm, float* __restrict__ hs){
  __shared__ float h_lds[2][8*68];
  __shared__ float gatebuf[64];
  const int tid  = threadIdx.x;
  const int g    = blockIdx.x;
  const int r    = tid>>3;            /* gate row 0..63 (= gate*16 + jl) */
  const int cch  = tid&7;             /* 64-wide k chunk */
  const int gate = r>>4, jl = r&15;
  const int R    = gate*HDIM + g*16 + jl;
  const int gi   = g*16 + tid;        /* valid for tid<16 (writers) */
  /* resident weight slice: W_hh_w[R][cch*64 .. +64) in 64 VGPRs */
  float4 w4[16];
  #pragma unroll
  for(int i=0;i<16;i++) w4[i] = *(const float4*)&Whh[(size_t)R*HDIM + cch*64 + 4*i];
  float cst = 0.f;
  float bsum[4], gxv[4];
  if (tid<16){
    #pragma unroll
    for(int q=0;q<4;q++){
      bsum[q] = bih[q*HDIM + gi] + bhh[q*HDIM + gi];
      gxv[q]  = gx[(size_t)0*G4H + q*HDIM + gi];   /* t=0 prefetch */
    }
  }

  #pragma unroll 1
  for(int t=0;t<SLEN;t++){
    /* poll h_t[tid]: 1-deep tag-match on packed {tag,value}, ping-pong row t&1 */
    float hv = 0.f;
    if (t>0){
      const u64* slot = &comm[(size_t)(t&1)*HDIM + tid];
      u64 v;
      do { v = __hip_atomic_load(slot, __ATOMIC_RELAXED, __HIP_MEMORY_SCOPE_AGENT); }
      while ((unsigned)(v>>32) != (unsigned)t);
      union{unsigned u; float f;} cv; cv.u = (unsigned)v; hv = cv.f;
    }
    const int par = t&1;
    h_lds[par][(tid>>6)*68 + (tid&63)] = hv;
    __syncthreads();
    /* 64-MAC partial dot from resident weights */
    float acc = 0.f;
    #pragma unroll
    for(int i=0;i<16;i++){
      float4 hh = *(const float4*)&h_lds[par][cch*68 + 4*i];
      acc = fmaf(w4[i].x, hh.x, acc);
      acc = fmaf(w4[i].y, hh.y, acc);
      acc = fmaf(w4[i].z, hh.z, acc);
      acc = fmaf(w4[i].w, hh.w, acc);
    }
    acc += __shfl_xor(acc,1);
    acc += __shfl_xor(acc,2);
    acc += __shfl_xor(acc,4);
    if (cch==0) gatebuf[r] = acc;
    __syncthreads();
    /* wave 0: gather gates, pointwise, coalesced 128B ping-pong store + hs */
    if (tid < 64){
      float gv  = gatebuf[tid];
      float a16 = __shfl_down(gv,16);
      float a32 = __shfl_down(gv,32);
      float a48 = __shfl_down(gv,48);
      if (tid<16){
        float gi_ = gv  + gxv[0] + bsum[0];
        float gf_ = a16 + gxv[1] + bsum[1];
        float gg_ = a32 + gxv[2] + bsum[2];
        float go_ = a48 + gxv[3] + bsum[3];
        float cn = sigf(gf_)*cst + sigf(gi_)*ftanh(gg_);
        float hn = sigf(go_)*ftanh(cn);
        cst = cn;
        union{float f; unsigned u;} hb; hb.f = hn;
        u64 pk = ((u64)(unsigned)(t+1)<<32) | (u64)hb.u;
        __hip_atomic_store(&comm[(size_t)((t+1)&1)*HDIM + gi], pk,
                           __ATOMIC_RELAXED, __HIP_MEMORY_SCOPE_AGENT);
        hs[(size_t)t*HDIM + gi] = hn;   /* history for k_out; off critical path */
        /* prefetch gx for t+1 AFTER the store (in flight across next poll) */
        if (t+1 < SLEN){
          #pragma unroll
          for(int q=0;q<4;q++) gxv[q] = gx[(size_t)(t+1)*G4H + q*HDIM + gi];
        }
      }
    }
  }
}

/* ------------- logits + log_softmax ------------- */
__global__ __launch_bounds__(256) void k_out(const float* __restrict__ hs,
        const float* __restrict__ Wout, const float* __restrict__ bout,
        float* __restrict__ out){
  __shared__ float hsub[HDIM];
  __shared__ float lg[NLBL];
  int s = blockIdx.x, tid = threadIdx.x;
  hsub[tid]     = hs[(size_t)s*HDIM + tid];
  hsub[tid+256] = hs[(size_t)s*HDIM + tid + 256];
  __syncthreads();
  int l = tid>>2, q = tid&3;
  float a = 0.f;
  const float* wrp = &Wout[(size_t)l*HDIM + q*128];
  const float* hr = &hsub[q*128];
  #pragma unroll 8
  for(int i=0;i<128;i++) a = fmaf(hr[i], wrp[i], a);
  a += __shfl_xor(a,1);
  a += __shfl_xor(a,2);
  if (q==0) lg[l] = a + bout[l];
  __syncthreads();
  if (tid < NLBL){
    float x = lg[tid];
    float mx = x;
    #pragma unroll
    for(int m=32;m>=1;m>>=1) mx = fmaxf(mx, __shfl_xor(mx,m));
    float ex = __expf(x-mx);
    float sm = ex;
    #pragma unroll
    for(int m=32;m>=1;m>>=1) sm += __shfl_xor(sm,m);
    out[(size_t)s*NLBL + tid] = x - mx - __logf(sm);
  }
}

extern "C" void kernel_launch(void* const* d_in, const int* in_sizes, int n_in,
                              void* d_out, int out_size, void* d_ws, size_t ws_size,
                              hipStream_t stream){
  const int*   sent  = (const int*)d_in[0];
  const float* chars = (const float*)d_in[1];
  const int*   lens  = (const int*)d_in[2];
  const float* emb   = (const float*)d_in[3];
  const float* Wihc  = (const float*)d_in[4];
  const float* Whhc  = (const float*)d_in[5];
  const float* bihc  = (const float*)d_in[6];
  const float* bhhc  = (const float*)d_in[7];
  const float* Wihw  = (const float*)d_in[8];
  const float* Whhw  = (const float*)d_in[9];
  const float* bihw  = (const float*)d_in[10];
  const float* bhhw  = (const float*)d_in[11];
  const float* Wout  = (const float*)d_in[12];
  const float* bout  = (const float*)d_in[13];
  float* out = (float*)d_out;

  /* workspace (floats): h_char 16384 | word_in 4096*260 | gx 4096*2048 |
     hs 4096*512 | comm 2*512 u64 (ping-pong, LLC-resident).
     comm tags are 1..4096 exact-match; 0xAA poison can never match. */
  float* h_char = (float*)d_ws;
  float* win    = h_char + 16384;
  float* gx     = win + (size_t)SLEN*KIN;
  float* hs     = gx + (size_t)SLEN*G4H;
  u64*   comm   = (u64*)(hs + (size_t)SLEN*HDIM);

  k_char_lstm<<<SLEN/256, 256, 0, stream>>>(chars,lens,Wihc,Whhc,bihc,bhhc,h_char);
  k_gather<<<SLEN, 64, 0, stream>>>(sent,emb,h_char,win);
  k_gemm_gx<<<dim3(SLEN/64, G4H/64), 256, 0, stream>>>(win,Wihw,gx);
  k_word_lstm<<<HDIM/16, 512, 0, stream>>>(gx,Whhw,bihw,bhhw,comm,hs);
  k_out<<<SLEN, 256, 0, stream>>>(hs,Wout,bout,out);
}

// Round 8
// 6104.636 us; speedup vs baseline: 1.3228x; 1.0631x over previous
//
#include <hip/hip_runtime.h>
#include <stdint.h>

#define SLEN 4096
#define CLEN 16
#define EDIM 256
#define HDIM 512
#define CHD  4
#define NLBL 64
#define KIN  260   /* EDIM + CHD */
#define G4H  2048  /* 4*HDIM */

typedef unsigned long long u64;

__device__ __forceinline__ float sigf(float x){ return 1.0f/(1.0f+__expf(-x)); }
/* fast tanh: 1 - 2/(e^(2x)+1); saturates correctly for |x| large */
__device__ __forceinline__ float ftanh(float x){
  float e = __expf(2.0f*x);
  return 1.0f - 2.0f/(e+1.0f);
}
/* broadcast lane i of own wave, VALU path (v_readlane), no LDS */
#define RLANE(x,i) __uint_as_float(__builtin_amdgcn_readlane(__float_as_uint(x),(i)))

/* ---------------- char-level LSTM: one thread per word ---------------- */
__global__ void k_char_lstm(const float* __restrict__ chars, const int* __restrict__ lens,
                            const float* __restrict__ Wih, const float* __restrict__ Whh,
                            const float* __restrict__ bih, const float* __restrict__ bhh,
                            float* __restrict__ h_char){
  int s = blockIdx.x*blockDim.x + threadIdx.x;
  if (s >= SLEN) return;
  float wih[16], bb[16], whh[16][4];
  #pragma unroll
  for(int r=0;r<16;r++){
    wih[r]=Wih[r]; bb[r]=bih[r]+bhh[r];
    #pragma unroll
    for(int k=0;k<4;k++) whh[r][k]=Whh[r*4+k];
  }
  float x[16];
  #pragma unroll
  for(int i=0;i<4;i++){
    float4 v = *(const float4*)&chars[s*CLEN + 4*i];
    x[4*i+0]=v.x; x[4*i+1]=v.y; x[4*i+2]=v.z; x[4*i+3]=v.w;
  }
  float h[4]={0,0,0,0}, c[4]={0,0,0,0};
  int len = lens[s];
  #pragma unroll 1
  for(int t=0;t<CLEN;t++){
    float g[16];
    #pragma unroll
    for(int r=0;r<16;r++){
      float a = fmaf(x[t], wih[r], bb[r]);
      #pragma unroll
      for(int k=0;k<4;k++) a = fmaf(h[k], whh[r][k], a);
      g[r]=a;
    }
    bool m = t < len;
    #pragma unroll
    for(int j=0;j<4;j++){
      float ig=sigf(g[j]), fg=sigf(g[4+j]), gg=ftanh(g[8+j]), og=sigf(g[12+j]);
      float cn = fg*c[j] + ig*gg;
      float hn = og*ftanh(cn);
      if(m){ c[j]=cn; h[j]=hn; }
    }
  }
  #pragma unroll
  for(int j=0;j<4;j++) h_char[s*CHD+j]=h[j];
}

/* ------------- gather emb rows + h_char into word_in[4096][260] ------------- */
__global__ void k_gather(const int* __restrict__ sent, const float* __restrict__ emb,
                         const float* __restrict__ h_char, float* __restrict__ win){
  int s = blockIdx.x; int l = threadIdx.x; /* 64 threads */
  int row = sent[s];
  float4 v = *(const float4*)&emb[(size_t)row*EDIM + 4*l];
  *(float4*)&win[(size_t)s*KIN + 4*l] = v;
  if (l < CHD) win[(size_t)s*KIN + EDIM + l] = h_char[s*CHD + l];
}

/* ------------- gx = word_in @ W_ih_w.T  (M=4096,N=2048,K=260) ------------- */
#define BK 20
__global__ __launch_bounds__(256) void k_gemm_gx(const float* __restrict__ win,
                          const float* __restrict__ Wihw, float* __restrict__ gx){
  __shared__ float As[BK][68];
  __shared__ float Bs[BK][68];
  int s0 = blockIdx.x*64, n0 = blockIdx.y*64;
  int tid = threadIdx.x;
  int tm = tid>>4, tn = tid&15;
  float acc[4][4] = {};
  for(int k0=0;k0<KIN;k0+=BK){
    __syncthreads();
    #pragma unroll
    for(int i=0;i<5;i++){
      int e = tid + i*256;
      int m = e/BK, kk = e - m*BK;
      As[kk][m] = win[(size_t)(s0+m)*KIN + k0+kk];
      Bs[kk][m] = Wihw[(size_t)(n0+m)*KIN + k0+kk];
    }
    __syncthreads();
    #pragma unroll
    for(int kk=0;kk<BK;kk++){
      float4 a4 = *(const float4*)&As[kk][tm*4];
      float4 b4 = *(const float4*)&Bs[kk][tn*4];
      float av[4]={a4.x,a4.y,a4.z,a4.w};
      float bv[4]={b4.x,b4.y,b4.z,b4.w};
      #pragma unroll
      for(int i=0;i<4;i++)
        #pragma unroll
        for(int j=0;j<4;j++)
          acc[i][j] = fmaf(av[i], bv[j], acc[i][j]);
    }
  }
  #pragma unroll
  for(int i=0;i<4;i++){
    float4 o; o.x=acc[i][0]; o.y=acc[i][1]; o.z=acc[i][2]; o.w=acc[i][3];
    *(float4*)&gx[(size_t)(s0+tm*4+i)*G4H + n0 + tn*4] = o;
  }
}

/* ------------- word-level LSTM: 32 persistent WGs, register-broadcast dot ---
   Wave w (tid>>6) owns k-chunk [64w, 64w+64); lane l (tid&63) is gate row l
   (gate = l>>4, h index jl = l&15). Lane l of wave w polls comm slot w*64+l:
   each wave polls EXACTLY the 64 h values it needs -> h never enters LDS;
   the dot is 64 x {v_readlane + v_fmac} pure-VALU (replaces the ~1500cy/step
   LDS-pipe wall of the b128 scheme). No barrier between poll and dot: a wave
   starts as soon as ITS producers are visible. ONE __syncthreads per step;
   pbuf is parity-double-buffered (lead >1 step impossible: polls gate on the
   wave-0 store). Comm: 2-row ping-pong (R7-proven, LLC-resident). */
__global__ __launch_bounds__(512) void k_word_lstm(const float* __restrict__ gx,
    const float* __restrict__ Whh, const float* __restrict__ bih, const float* __restrict__ bhh,
    u64* __restrict__ comm, float* __restrict__ hs){
  __shared__ float pbuf[2][8][64];
  const int tid = threadIdx.x;
  const int g   = blockIdx.x;
  const int w   = tid>>6;            /* wave = k-chunk 0..7 */
  const int l   = tid&63;            /* gate row 0..63 */
  const int R   = (l>>4)*HDIM + g*16 + (l&15);
  const int gi  = g*16 + tid;        /* valid for tid<16 (writers) */
  /* resident weight slice: W_hh_w[R][w*64 .. +64) in 64 VGPRs */
  float4 w4[16];
  #pragma unroll
  for(int i=0;i<16;i++) w4[i] = *(const float4*)&Whh[(size_t)R*HDIM + w*64 + 4*i];
  float cst = 0.f;
  float bsum[4], gxv[4];
  if (tid<16){
    #pragma unroll
    for(int q=0;q<4;q++){
      bsum[q] = bih[q*HDIM + gi] + bhh[q*HDIM + gi];
      gxv[q]  = gx[(size_t)0*G4H + q*HDIM + gi];   /* t=0 prefetch */
    }
  }

  #pragma unroll 1
  for(int t=0;t<SLEN;t++){
    const int par = t&1;
    /* poll own slot: 1-deep tag-match, ping-pong row (R7-proven) */
    float hv = 0.f;
    if (t>0){
      const u64* slot = &comm[(size_t)par*HDIM + w*64 + l];
      u64 v;
      do { v = __hip_atomic_load(slot, __ATOMIC_RELAXED, __HIP_MEMORY_SCOPE_AGENT); }
      while ((unsigned)(v>>32) != (unsigned)t);
      union{unsigned u; float f;} cv; cv.u = (unsigned)v; hv = cv.f;
    }
    /* 64-MAC dot, h broadcast via v_readlane (4 acc chains) */
    float a0=0.f, a1=0.f, a2=0.f, a3=0.f;
    #pragma unroll
    for(int i=0;i<16;i++){
      float4 wv = w4[i];
      a0 = fmaf(wv.x, RLANE(hv,4*i+0), a0);
      a1 = fmaf(wv.y, RLANE(hv,4*i+1), a1);
      a2 = fmaf(wv.z, RLANE(hv,4*i+2), a2);
      a3 = fmaf(wv.w, RLANE(hv,4*i+3), a3);
    }
    pbuf[par][w][l] = (a0+a1)+(a2+a3);
    __syncthreads();                      /* the ONLY barrier per step */
    /* wave 0: sum 8 partials per row, gather gates, pointwise, 128B store */
    if (tid < 64){
      const float* pb = &pbuf[par][0][0];
      float s = pb[tid];
      #pragma unroll
      for(int q=1;q<8;q++) s += pb[q*64 + tid];
      float a16 = __shfl_down(s,16);
      float a32 = __shfl_down(s,32);
      float a48 = __shfl_down(s,48);
      if (tid<16){
        float gi_ = s   + gxv[0] + bsum[0];
        float gf_ = a16 + gxv[1] + bsum[1];
        float gg_ = a32 + gxv[2] + bsum[2];
        float go_ = a48 + gxv[3] + bsum[3];
        float cn = sigf(gf_)*cst + sigf(gi_)*ftanh(gg_);
        float hn = sigf(go_)*ftanh(cn);
        cst = cn;
        union{float f; unsigned u;} hb; hb.f = hn;
        u64 pk = ((u64)(unsigned)(t+1)<<32) | (u64)hb.u;
        __hip_atomic_store(&comm[(size_t)((t+1)&1)*HDIM + gi], pk,
                           __ATOMIC_RELAXED, __HIP_MEMORY_SCOPE_AGENT);
        hs[(size_t)t*HDIM + gi] = hn;     /* history for k_out; off critical path */
        if (t+1 < SLEN){                  /* gx prefetch, in flight over next poll */
          #pragma unroll
          for(int q=0;q<4;q++) gxv[q] = gx[(size_t)(t+1)*G4H + q*HDIM + gi];
        }
      }
    }
  }
}

/* ------------- logits + log_softmax ------------- */
__global__ __launch_bounds__(256) void k_out(const float* __restrict__ hs,
        const float* __restrict__ Wout, const float* __restrict__ bout,
        float* __restrict__ out){
  __shared__ float hsub[HDIM];
  __shared__ float lg[NLBL];
  int s = blockIdx.x, tid = threadIdx.x;
  hsub[tid]     = hs[(size_t)s*HDIM + tid];
  hsub[tid+256] = hs[(size_t)s*HDIM + tid + 256];
  __syncthreads();
  int l = tid>>2, q = tid&3;
  float a = 0.f;
  const float* wrp = &Wout[(size_t)l*HDIM + q*128];
  const float* hr = &hsub[q*128];
  #pragma unroll 8
  for(int i=0;i<128;i++) a = fmaf(hr[i], wrp[i], a);
  a += __shfl_xor(a,1);
  a += __shfl_xor(a,2);
  if (q==0) lg[l] = a + bout[l];
  __syncthreads();
  if (tid < NLBL){
    float x = lg[tid];
    float mx = x;
    #pragma unroll
    for(int m=32;m>=1;m>>=1) mx = fmaxf(mx, __shfl_xor(mx,m));
    float ex = __expf(x-mx);
    float sm = ex;
    #pragma unroll
    for(int m=32;m>=1;m>>=1) sm += __shfl_xor(sm,m);
    out[(size_t)s*NLBL + tid] = x - mx - __logf(sm);
  }
}

extern "C" void kernel_launch(void* const* d_in, const int* in_sizes, int n_in,
                              void* d_out, int out_size, void* d_ws, size_t ws_size,
                              hipStream_t stream){
  const int*   sent  = (const int*)d_in[0];
  const float* chars = (const float*)d_in[1];
  const int*   lens  = (const int*)d_in[2];
  const float* emb   = (const float*)d_in[3];
  const float* Wihc  = (const float*)d_in[4];
  const float* Whhc  = (const float*)d_in[5];
  const float* bihc  = (const float*)d_in[6];
  const float* bhhc  = (const float*)d_in[7];
  const float* Wihw  = (const float*)d_in[8];
  const float* Whhw  = (const float*)d_in[9];
  const float* bihw  = (const float*)d_in[10];
  const float* bhhw  = (const float*)d_in[11];
  const float* Wout  = (const float*)d_in[12];
  const float* bout  = (const float*)d_in[13];
  float* out = (float*)d_out;

  /* workspace (floats): h_char 16384 | word_in 4096*260 | gx 4096*2048 |
     hs 4096*512 | comm 2*512 u64 (ping-pong, LLC-resident).
     comm tags are 1..4096 exact-match; 0xAA poison can never match. */
  float* h_char = (float*)d_ws;
  float* win    = h_char + 16384;
  float* gx     = win + (size_t)SLEN*KIN;
  float* hs     = gx + (size_t)SLEN*G4H;
  u64*   comm   = (u64*)(hs + (size_t)SLEN*HDIM);

  k_char_lstm<<<SLEN/256, 256, 0, stream>>>(chars,lens,Wihc,Whhc,bihc,bhhc,h_char);
  k_gather<<<SLEN, 64, 0, stream>>>(sent,emb,h_char,win);
  k_gemm_gx<<<dim3(SLEN/64, G4H/64), 256, 0, stream>>>(win,Wihw,gx);
  k_word_lstm<<<HDIM/16, 512, 0, stream>>>(gx,Whhw,bihw,bhhw,comm,hs);
  k_out<<<SLEN, 256, 0, stream>>>(hs,Wout,bout,out);
}